// Round 1
// baseline (77.591 us; speedup 1.0000x reference)
//
#include <hip/hip_runtime.h>
#include <math.h>

#define NQ 300
#define NT 30
#define NC 10
#define NTH 320
#define NWAVE (NTH/64)
#define INFF 3.0e38f

__device__ __forceinline__ float sigf(float x){ return 1.0f/(1.0f + expf(-x)); }
__device__ __forceinline__ float softplusf(float x){ return fmaxf(x,0.0f) + log1pf(expf(-fabsf(x))); }

// One block per batch element. Builds the 30x300 cost matrix in LDS, runs
// Jonker-Volgenant Hungarian (rows = targets, cols = queries), then computes
// this batch's loss contribution (focal t=0 over all logits + matched-pair
// corrections) and writes it to part[b]. Deterministic: no atomics.
__global__ __launch_bounds__(NTH) void hm_main(
    const float* __restrict__ logits,   // [64,300,10]
    const float* __restrict__ pbox,     // [64,300,4] cxcywh
    const int*   __restrict__ labels,   // [64,30]
    const float* __restrict__ tbox,     // [64,30,4] cxcywh
    float* __restrict__ part)           // [64]
{
  const int b = blockIdx.x;
  const int tid = threadIdx.x;

  __shared__ float D[NT*NQ];
  __shared__ float qraw[NQ][4], qxy[NQ][4], qarea[NQ];
  __shared__ float traw[NT][4], txy[NT][4], tarea[NT];
  __shared__ int   tlab[NT];
  __shared__ float uu[NT+1], vv[NQ+1], minv[NQ+1];
  __shared__ int   way[NQ+1], pp[NQ+1], used[NQ+1];
  __shared__ float wv[NWAVE]; __shared__ int wj[NWAVE];
  __shared__ float sdelta; __shared__ int sj0;
  __shared__ float redw[NWAVE];

  // stage query boxes (raw + xyxy + area)
  for (int q = tid; q < NQ; q += NTH) {
    const float* s = pbox + ((size_t)b*NQ + q)*4;
    float cx=s[0], cy=s[1], w=s[2], h=s[3];
    qraw[q][0]=cx; qraw[q][1]=cy; qraw[q][2]=w; qraw[q][3]=h;
    float x0=cx-0.5f*w, y0=cy-0.5f*h, x1=cx+0.5f*w, y1=cy+0.5f*h;
    qxy[q][0]=x0; qxy[q][1]=y0; qxy[q][2]=x1; qxy[q][3]=y1;
    qarea[q]=(x1-x0)*(y1-y0);
  }
  if (tid < NT) {
    const float* s = tbox + ((size_t)b*NT + tid)*4;
    float cx=s[0], cy=s[1], w=s[2], h=s[3];
    traw[tid][0]=cx; traw[tid][1]=cy; traw[tid][2]=w; traw[tid][3]=h;
    float x0=cx-0.5f*w, y0=cy-0.5f*h, x1=cx+0.5f*w, y1=cy+0.5f*h;
    txy[tid][0]=x0; txy[tid][1]=y0; txy[tid][2]=x1; txy[tid][3]=y1;
    tarea[tid]=(x1-x0)*(y1-y0);
    tlab[tid]=labels[b*NT + tid];
  }
  for (int j = tid; j <= NQ; j += NTH) { vv[j]=0.f; pp[j]=0; way[j]=0; }
  if (tid <= NT) uu[tid]=0.f;
  __syncthreads();

  // cost fill: D[i][q] = 5*L1 + 2*(-sigmoid(logit)) + 2*(-giou)
  for (int idx = tid; idx < NT*NQ; idx += NTH) {
    int i = idx / NQ, q = idx - i*NQ;
    float cb = fabsf(qraw[q][0]-traw[i][0]) + fabsf(qraw[q][1]-traw[i][1])
             + fabsf(qraw[q][2]-traw[i][2]) + fabsf(qraw[q][3]-traw[i][3]);
    float lt0=fmaxf(qxy[q][0],txy[i][0]), lt1=fmaxf(qxy[q][1],txy[i][1]);
    float rb0=fminf(qxy[q][2],txy[i][2]), rb1=fminf(qxy[q][3],txy[i][3]);
    float iw=fmaxf(rb0-lt0,0.f), ih=fmaxf(rb1-lt1,0.f);
    float inter=iw*ih;
    float uni=qarea[q]+tarea[i]-inter;
    float iou=inter/uni;
    float c0=fminf(qxy[q][0],txy[i][0]), c1=fminf(qxy[q][1],txy[i][1]);
    float c2=fmaxf(qxy[q][2],txy[i][2]), c3=fmaxf(qxy[q][3],txy[i][3]);
    float cw=fmaxf(c2-c0,0.f), ch=fmaxf(c3-c1,0.f);
    float areac=cw*ch;
    float g=iou-(areac-uni)/areac;
    float pcls=sigf(logits[((size_t)b*NQ+q)*NC + tlab[i]]);
    D[idx] = 5.f*cb - 2.f*pcls - 2.f*g;
  }
  __syncthreads();

  // JV Hungarian. pp[j] = 1-based row assigned to column j (0 = free).
  for (int it = 1; it <= NT; ++it) {
    if (tid == 0) { pp[0]=it; sj0=0; }
    for (int j = tid; j <= NQ; j += NTH) { minv[j]=INFF; used[j]=0; }
    __syncthreads();
    for (;;) {
      if (tid == 0) used[sj0]=1;
      __syncthreads();
      int j0=sj0, i0=pp[j0];
      float ui0=uu[i0];
      float lval=INFF; int lj=0x7fffffff;
      if (tid < NQ) {
        int j=tid+1;
        if (!used[j]) {
          float cur = D[(i0-1)*NQ + tid] - ui0 - vv[j];
          if (cur < minv[j]) { minv[j]=cur; way[j]=j0; }
          lval=minv[j]; lj=j;
        }
      }
      #pragma unroll
      for (int off=32; off; off>>=1) {
        float ov=__shfl_down(lval,off); int oj=__shfl_down(lj,off);
        if (ov<lval || (ov==lval && oj<lj)) { lval=ov; lj=oj; }
      }
      if ((tid&63)==0){ wv[tid>>6]=lval; wj[tid>>6]=lj; }
      __syncthreads();
      if (tid==0) {
        float bv=wv[0]; int bj=wj[0];
        for (int w=1; w<NWAVE; ++w)
          if (wv[w]<bv || (wv[w]==bv && wj[w]<bj)) { bv=wv[w]; bj=wj[w]; }
        sdelta=bv; sj0=bj;
      }
      __syncthreads();
      float delta=sdelta; int j1=sj0;
      if (tid <= NQ) {
        if (used[tid]) { uu[pp[tid]] += delta; vv[tid] -= delta; }
        else minv[tid] -= delta;
      }
      __syncthreads();
      if (pp[j1]==0) break;   // uniform: all threads read same pp[j1]
    }
    if (tid==0) {             // augment along 'way'
      int j0=sj0;
      while (j0) { int jn=way[j0]; pp[j0]=pp[jn]; j0=jn; }
    }
    __syncthreads();
  }

  // losses: matched-pair terms (owned by the column's thread)
  float tot = 0.f;
  if (tid < NQ) {
    int j=tid+1, row=pp[j];
    if (row > 0) {
      int ti=row-1, q=j-1;
      float l1 = fabsf(qraw[q][0]-traw[ti][0]) + fabsf(qraw[q][1]-traw[ti][1])
               + fabsf(qraw[q][2]-traw[ti][2]) + fabsf(qraw[q][3]-traw[ti][3]);
      float lt0=fmaxf(qxy[q][0],txy[ti][0]), lt1=fmaxf(qxy[q][1],txy[ti][1]);
      float rb0=fminf(qxy[q][2],txy[ti][2]), rb1=fminf(qxy[q][3],txy[ti][3]);
      float iw=fmaxf(rb0-lt0,0.f), ih=fmaxf(rb1-lt1,0.f);
      float inter=iw*ih;
      float uni=qarea[q]+tarea[ti]-inter;
      float iou=inter/uni;
      float c0=fminf(qxy[q][0],txy[ti][0]), c1=fminf(qxy[q][1],txy[ti][1]);
      float c2=fmaxf(qxy[q][2],txy[ti][2]), c3=fmaxf(qxy[q][3],txy[ti][3]);
      float cw=fmaxf(c2-c0,0.f), ch=fmaxf(c3-c1,0.f);
      float areac=cw*ch;
      float g=iou-(areac-uni)/areac;
      // focal correction: replace t=0 term with t=1 term at the matched class
      float x = logits[((size_t)b*NQ+q)*NC + tlab[ti]];
      float pr = sigf(x);
      float sp = softplusf(x);
      float term0 = 0.75f*sp*pr*pr;
      float term1 = 0.25f*(sp - x)*(1.f-pr)*(1.f-pr);
      tot = (term1-term0) + 5.f*l1 + 2.f*(1.f-g);
    }
  }
  // focal t=0 baseline over this batch's 300x10 logits
  for (int e = tid; e < NQ*NC; e += NTH) {
    float x = logits[(size_t)b*NQ*NC + e];
    float pr = sigf(x);
    tot += 0.75f * softplusf(x) * pr * pr;
  }
  #pragma unroll
  for (int off=32; off; off>>=1) tot += __shfl_down(tot, off);
  if ((tid&63)==0) redw[tid>>6]=tot;
  __syncthreads();
  if (tid==0) {
    float s=0.f;
    for (int w=0; w<NWAVE; ++w) s+=redw[w];
    part[b] = s;
  }
}

__global__ void hm_fin(const float* __restrict__ part, float* __restrict__ out) {
  float s = part[threadIdx.x];
  #pragma unroll
  for (int off=32; off; off>>=1) s += __shfl_down(s, off);
  if (threadIdx.x==0) out[0] = s * (1.0f/1920.0f);
}

extern "C" void kernel_launch(void* const* d_in, const int* in_sizes, int n_in,
                              void* d_out, int out_size, void* d_ws, size_t ws_size,
                              hipStream_t stream) {
  const float* logits = (const float*)d_in[0];
  const float* pbox   = (const float*)d_in[1];
  const int*   labels = (const int*)d_in[2];
  const float* tbox   = (const float*)d_in[3];
  float* partials = (float*)d_ws;           // 64 floats, fully overwritten each launch
  hm_main<<<dim3(64), dim3(NTH), 0, stream>>>(logits, pbox, labels, tbox, partials);
  hm_fin<<<dim3(1), dim3(64), 0, stream>>>(partials, (float*)d_out);
}

// Round 2
// 66.249 us; speedup vs baseline: 1.1712x; 1.1712x over previous
//
#include <hip/hip_runtime.h>
#include <math.h>

#define NQ 300
#define NT 30
#define NC 10
#define NTH 320
#define NWAVE (NTH/64)
#define INFF 3.0e38f

__device__ __forceinline__ float sigf(float x){ return 1.0f/(1.0f + expf(-x)); }
__device__ __forceinline__ float softplusf(float x){ return fmaxf(x,0.0f) + log1pf(expf(-fabsf(x))); }

// One block per batch element. 320 threads build the 30x300 cost matrix in
// LDS; wave 0 alone runs JV Hungarian (lockstep, zero barriers, column state
// in registers: 5 cols/lane); then all threads compute the loss contribution.
__global__ __launch_bounds__(NTH) void hm_main(
    const float* __restrict__ logits,   // [64,300,10]
    const float* __restrict__ pbox,     // [64,300,4] cxcywh
    const int*   __restrict__ labels,   // [64,30]
    const float* __restrict__ tbox,     // [64,30,4] cxcywh
    float* __restrict__ part)           // [64]
{
  const int b = blockIdx.x;
  const int tid = threadIdx.x;

  __shared__ float D[NT*NQ];
  __shared__ float psm[NQ*NC];          // sigmoid(logits) table
  __shared__ float qraw[NQ][4], qxy[NQ][4], qarea[NQ];
  __shared__ float traw[NT][4], txy[NT][4], tarea[NT];
  __shared__ int   tlab[NT];
  __shared__ float uu[NT+1];            // row duals (1-based)
  __shared__ int   pcol[NQ];            // 0 = free, else assigned row 1..30
  __shared__ int   wayl[NQ];            // predecessor column (-1 = virtual)
  __shared__ float redw[NWAVE];

  // stage query boxes (raw + xyxy + area)
  for (int q = tid; q < NQ; q += NTH) {
    const float* s = pbox + ((size_t)b*NQ + q)*4;
    float cx=s[0], cy=s[1], w=s[2], h=s[3];
    qraw[q][0]=cx; qraw[q][1]=cy; qraw[q][2]=w; qraw[q][3]=h;
    float x0=cx-0.5f*w, y0=cy-0.5f*h, x1=cx+0.5f*w, y1=cy+0.5f*h;
    qxy[q][0]=x0; qxy[q][1]=y0; qxy[q][2]=x1; qxy[q][3]=y1;
    qarea[q]=(x1-x0)*(y1-y0);
  }
  if (tid < NT) {
    const float* s = tbox + ((size_t)b*NT + tid)*4;
    float cx=s[0], cy=s[1], w=s[2], h=s[3];
    traw[tid][0]=cx; traw[tid][1]=cy; traw[tid][2]=w; traw[tid][3]=h;
    float x0=cx-0.5f*w, y0=cy-0.5f*h, x1=cx+0.5f*w, y1=cy+0.5f*h;
    txy[tid][0]=x0; txy[tid][1]=y0; txy[tid][2]=x1; txy[tid][3]=y1;
    tarea[tid]=(x1-x0)*(y1-y0);
    tlab[tid]=labels[b*NT + tid];
  }
  if (tid <= NT) uu[tid]=0.f;
  for (int j=tid; j<NQ; j+=NTH) pcol[j]=0;

  // sigmoid table + focal t=0 baseline partial sum (all 300x10 logits)
  float tot = 0.f;
  for (int e = tid; e < NQ*NC; e += NTH) {
    float x = logits[(size_t)b*NQ*NC + e];
    float pr = sigf(x);
    psm[e] = pr;
    tot += 0.75f * softplusf(x) * pr * pr;
  }
  __syncthreads();

  // cost fill: D[i][q] = 5*L1 - 2*sigmoid - 2*giou
  for (int idx = tid; idx < NT*NQ; idx += NTH) {
    int i = idx / NQ, q = idx - i*NQ;
    float cb = fabsf(qraw[q][0]-traw[i][0]) + fabsf(qraw[q][1]-traw[i][1])
             + fabsf(qraw[q][2]-traw[i][2]) + fabsf(qraw[q][3]-traw[i][3]);
    float lt0=fmaxf(qxy[q][0],txy[i][0]), lt1=fmaxf(qxy[q][1],txy[i][1]);
    float rb0=fminf(qxy[q][2],txy[i][2]), rb1=fminf(qxy[q][3],txy[i][3]);
    float iw=fmaxf(rb0-lt0,0.f), ih=fmaxf(rb1-lt1,0.f);
    float inter=iw*ih;
    float uni=qarea[q]+tarea[i]-inter;
    float iou=inter/uni;
    float c0=fminf(qxy[q][0],txy[i][0]), c1=fminf(qxy[q][1],txy[i][1]);
    float c2=fmaxf(qxy[q][2],txy[i][2]), c3=fmaxf(qxy[q][3],txy[i][3]);
    float cw=fmaxf(c2-c0,0.f), ch=fmaxf(c3-c1,0.f);
    float areac=cw*ch;
    float g=iou-(areac-uni)/areac;
    float pcls = psm[q*NC + tlab[i]];
    D[idx] = 5.f*cb - 2.f*pcls - 2.f*g;
  }
  __syncthreads();

  // ---- single-wave JV Hungarian (wave 0 only, no barriers inside) ----
  if (tid < 64) {
    const int lane = tid;
    float vvr[5] = {0.f,0.f,0.f,0.f,0.f};   // column duals, col = lane + 64k
    const bool v4 = lane < (NQ - 256);      // k=4 valid only for lane<44
    for (int it = 1; it <= NT; ++it) {
      float minvr[5] = {INFF,INFF,INFF,INFF,INFF};
      int   rowc[5]  = {0,0,0,0,0};         // assigned row of used cols
      int   usedm = 0;
      int   j0 = -1, i0 = it, j1 = 0;
      for (;;) {
        float ui0 = uu[i0];
        const float* Drow = &D[(i0-1)*NQ];
        float lval = INFF; int lidx = 0x7fffffff;
        #pragma unroll
        for (int k = 0; k < 5; ++k) {
          int c = lane + (k<<6);
          if ((k < 4 || v4) && !((usedm>>k)&1)) {
            float cur = Drow[c] - ui0 - vvr[k];
            if (cur < minvr[k]) { minvr[k] = cur; wayl[c] = j0; }
            if (minvr[k] < lval) { lval = minvr[k]; lidx = c; } // c ascending -> first-min kept
          }
        }
        // 64-lane butterfly argmin, tie-break smallest column (np.argmin)
        #pragma unroll
        for (int m = 1; m < 64; m <<= 1) {
          float ov = __shfl_xor(lval, m); int oj = __shfl_xor(lidx, m);
          if (ov < lval || (ov == lval && oj < lidx)) { lval = ov; lidx = oj; }
        }
        const float delta = lval; j1 = lidx;
        // dual updates
        if (lane == 0) uu[it] += delta;     // virtual column 0 (row 'it')
        #pragma unroll
        for (int k = 0; k < 5; ++k) {
          if ((usedm>>k)&1) { vvr[k] -= delta; uu[rowc[k]] += delta; }
          else              { minvr[k] -= delta; }
        }
        int pj1 = pcol[j1];
        if (pj1 == 0) break;                // free column reached
        if (lane == (j1 & 63)) {            // owner marks j1 used, caches its row
          int s = j1 >> 6;
          usedm |= (1 << s);
          #pragma unroll
          for (int k = 0; k < 5; ++k) if (k == s) rowc[k] = pj1;
        }
        j0 = j1; i0 = pj1;
      }
      // augment along 'way' (all lanes lockstep, identical writes)
      int j = j1;
      for (;;) {
        int jp = wayl[j];
        int r = (jp < 0) ? it : pcol[jp];
        pcol[j] = r;
        if (jp < 0) break;
        j = jp;
      }
    }
  }
  __syncthreads();

  // matched-pair losses (column's thread owns it)
  if (tid < NQ) {
    int row = pcol[tid];
    if (row > 0) {
      int ti = row-1, q = tid;
      float l1 = fabsf(qraw[q][0]-traw[ti][0]) + fabsf(qraw[q][1]-traw[ti][1])
               + fabsf(qraw[q][2]-traw[ti][2]) + fabsf(qraw[q][3]-traw[ti][3]);
      float lt0=fmaxf(qxy[q][0],txy[ti][0]), lt1=fmaxf(qxy[q][1],txy[ti][1]);
      float rb0=fminf(qxy[q][2],txy[ti][2]), rb1=fminf(qxy[q][3],txy[ti][3]);
      float iw=fmaxf(rb0-lt0,0.f), ih=fmaxf(rb1-lt1,0.f);
      float inter=iw*ih;
      float uni=qarea[q]+tarea[ti]-inter;
      float iou=inter/uni;
      float c0=fminf(qxy[q][0],txy[ti][0]), c1=fminf(qxy[q][1],txy[ti][1]);
      float c2=fmaxf(qxy[q][2],txy[ti][2]), c3=fmaxf(qxy[q][3],txy[ti][3]);
      float cw=fmaxf(c2-c0,0.f), ch=fmaxf(c3-c1,0.f);
      float areac=cw*ch;
      float g=iou-(areac-uni)/areac;
      // focal: replace t=0 term with t=1 term at the matched class
      float x  = logits[((size_t)b*NQ+q)*NC + tlab[ti]];
      float pr = psm[q*NC + tlab[ti]];
      float sp = softplusf(x);
      float term0 = 0.75f*sp*pr*pr;
      float term1 = 0.25f*(sp - x)*(1.f-pr)*(1.f-pr);
      tot += (term1 - term0) + 5.f*l1 + 2.f*(1.f-g);
    }
  }
  // block reduction
  #pragma unroll
  for (int off=32; off; off>>=1) tot += __shfl_down(tot, off);
  if ((tid&63)==0) redw[tid>>6]=tot;
  __syncthreads();
  if (tid==0) {
    float s=0.f;
    for (int w=0; w<NWAVE; ++w) s+=redw[w];
    part[b] = s;
  }
}

__global__ void hm_fin(const float* __restrict__ part, float* __restrict__ out) {
  float s = part[threadIdx.x];
  #pragma unroll
  for (int off=32; off; off>>=1) s += __shfl_down(s, off);
  if (threadIdx.x==0) out[0] = s * (1.0f/1920.0f);
}

extern "C" void kernel_launch(void* const* d_in, const int* in_sizes, int n_in,
                              void* d_out, int out_size, void* d_ws, size_t ws_size,
                              hipStream_t stream) {
  const float* logits = (const float*)d_in[0];
  const float* pbox   = (const float*)d_in[1];
  const int*   labels = (const int*)d_in[2];
  const float* tbox   = (const float*)d_in[3];
  float* partials = (float*)d_ws;   // 64 floats, fully overwritten each launch
  hm_main<<<dim3(64), dim3(NTH), 0, stream>>>(logits, pbox, labels, tbox, partials);
  hm_fin<<<dim3(1), dim3(64), 0, stream>>>(partials, (float*)d_out);
}

// Round 3
// 41.250 us; speedup vs baseline: 1.8810x; 1.6060x over previous
//
#include <hip/hip_runtime.h>
#include <math.h>

#define NQ 300
#define NT 30
#define NC 10
#define NTH 320
#define NWAVE (NTH/64)
#define INFF 3.0e38f

__device__ __forceinline__ float sigf(float x){ return 1.0f/(1.0f + expf(-x)); }
__device__ __forceinline__ float softplusf(float x){ return fmaxf(x,0.0f) + log1pf(expf(-fabsf(x))); }

// One block per batch element. 320 threads build the 30x300 cost matrix in
// LDS and the 30 row-argminima; wave 0 greedily assigns rows to free argmin
// columns (LAPJV-style dual init: u=rowmin, v=0 keeps exactness), then runs
// JV shortest-augmenting-path only for the few contested rows. Unique optimum
// (continuous random costs) => same assignment as the reference's Hungarian.
__global__ __launch_bounds__(NTH) void hm_main(
    const float* __restrict__ logits,   // [64,300,10]
    const float* __restrict__ pbox,     // [64,300,4] cxcywh
    const int*   __restrict__ labels,   // [64,30]
    const float* __restrict__ tbox,     // [64,30,4] cxcywh
    float* __restrict__ part)           // [64]
{
  const int b = blockIdx.x;
  const int tid = threadIdx.x;

  __shared__ float D[NT*NQ];
  __shared__ float psm[NQ*NC];          // sigmoid(logits) table
  __shared__ float qraw[NQ][4], qxy[NQ][4], qarea[NQ];
  __shared__ float traw[NT][4], txy[NT][4], tarea[NT];
  __shared__ int   tlab[NT];
  __shared__ float uu[NT+1];            // row duals (1-based)
  __shared__ int   pcol[NQ];            // 0 = free, else assigned row 1..30
  __shared__ int   wayl[NQ];            // predecessor column (-1 = virtual)
  __shared__ int   rargm[NT];           // row argmin column
  __shared__ float redw[NWAVE];

  // stage query boxes (raw + xyxy + area)
  for (int q = tid; q < NQ; q += NTH) {
    const float* s = pbox + ((size_t)b*NQ + q)*4;
    float cx=s[0], cy=s[1], w=s[2], h=s[3];
    qraw[q][0]=cx; qraw[q][1]=cy; qraw[q][2]=w; qraw[q][3]=h;
    float x0=cx-0.5f*w, y0=cy-0.5f*h, x1=cx+0.5f*w, y1=cy+0.5f*h;
    qxy[q][0]=x0; qxy[q][1]=y0; qxy[q][2]=x1; qxy[q][3]=y1;
    qarea[q]=(x1-x0)*(y1-y0);
  }
  if (tid < NT) {
    const float* s = tbox + ((size_t)b*NT + tid)*4;
    float cx=s[0], cy=s[1], w=s[2], h=s[3];
    traw[tid][0]=cx; traw[tid][1]=cy; traw[tid][2]=w; traw[tid][3]=h;
    float x0=cx-0.5f*w, y0=cy-0.5f*h, x1=cx+0.5f*w, y1=cy+0.5f*h;
    txy[tid][0]=x0; txy[tid][1]=y0; txy[tid][2]=x1; txy[tid][3]=y1;
    tarea[tid]=(x1-x0)*(y1-y0);
    tlab[tid]=labels[b*NT + tid];
  }
  for (int j=tid; j<NQ; j+=NTH) pcol[j]=0;

  // sigmoid table + focal t=0 baseline partial sum (all 300x10 logits)
  float tot = 0.f;
  for (int e = tid; e < NQ*NC; e += NTH) {
    float x = logits[(size_t)b*NQ*NC + e];
    float pr = sigf(x);
    psm[e] = pr;
    tot += 0.75f * softplusf(x) * pr * pr;
  }
  __syncthreads();

  // cost fill: D[i][q] = 5*L1 - 2*sigmoid - 2*giou
  for (int idx = tid; idx < NT*NQ; idx += NTH) {
    int i = idx / NQ, q = idx - i*NQ;
    float cb = fabsf(qraw[q][0]-traw[i][0]) + fabsf(qraw[q][1]-traw[i][1])
             + fabsf(qraw[q][2]-traw[i][2]) + fabsf(qraw[q][3]-traw[i][3]);
    float lt0=fmaxf(qxy[q][0],txy[i][0]), lt1=fmaxf(qxy[q][1],txy[i][1]);
    float rb0=fminf(qxy[q][2],txy[i][2]), rb1=fminf(qxy[q][3],txy[i][3]);
    float iw=fmaxf(rb0-lt0,0.f), ih=fmaxf(rb1-lt1,0.f);
    float inter=iw*ih;
    float uni=qarea[q]+tarea[i]-inter;
    float iou=inter/uni;
    float c0=fminf(qxy[q][0],txy[i][0]), c1=fminf(qxy[q][1],txy[i][1]);
    float c2=fmaxf(qxy[q][2],txy[i][2]), c3=fmaxf(qxy[q][3],txy[i][3]);
    float cw=fmaxf(c2-c0,0.f), ch=fmaxf(c3-c1,0.f);
    float areac=cw*ch;
    float g=iou-(areac-uni)/areac;
    float pcls = psm[q*NC + tlab[i]];
    D[idx] = 5.f*cb - 2.f*pcls - 2.f*g;
  }
  __syncthreads();

  // Phase 1: row minima + argmins in parallel (wave w -> rows 6w..6w+5)
  {
    const int wv = tid>>6, ln = tid&63;
    for (int i = wv*6; i < wv*6+6; ++i) {
      float bv=INFF; int bj=0x7fffffff;
      #pragma unroll
      for (int k=0;k<5;++k) {
        int c = ln+(k<<6);
        if (k<4 || ln < (NQ-256)) {
          float d = D[i*NQ+c];
          if (d < bv) { bv=d; bj=c; }      // ascending c -> first-min kept
        }
      }
      #pragma unroll
      for (int m=1;m<64;m<<=1) {
        float ov=__shfl_xor(bv,m); int oj=__shfl_xor(bj,m);
        if (ov<bv || (ov==bv && oj<bj)) { bv=ov; bj=oj; }
      }
      if (ln==0) { uu[i+1]=bv; rargm[i]=bj; }   // u[i] = row min (feasible dual)
    }
  }
  __syncthreads();

  // ---- wave 0: greedy assignment + SAP for contested rows ----
  if (tid < 64) {
    const int lane = tid;
    float vvr[5] = {0.f,0.f,0.f,0.f,0.f};   // column duals, col = lane + 64k
    const bool v4 = lane < (NQ - 256);
    int jm = (lane < NT) ? rargm[lane] : 0;
    int claim = 0;                           // greedy-claim bits for my 5 cols
    unsigned freerows = 0u;
    #pragma unroll
    for (int r = 0; r < NT; ++r) {
      int jmr = __shfl(jm, r);               // uniform r -> readlane
      bool avail = (lane == (jmr & 63)) && !((claim >> (jmr >> 6)) & 1);
      if (__ballot(avail)) {
        if (avail) { claim |= (1 << (jmr >> 6)); pcol[jmr] = r + 1; }
      } else freerows |= (1u << r);
    }
    // shortest augmenting path for each unassigned row
    while (freerows) {
      int fr = __builtin_ctz(freerows); freerows &= (freerows - 1);
      const int it = fr + 1;
      float minvr[5] = {INFF,INFF,INFF,INFF,INFF};
      int   rowc[5]  = {0,0,0,0,0};
      int   usedm = 0;
      int   j0 = -1, i0 = it, j1 = 0;
      for (;;) {
        float ui0 = uu[i0];
        const float* Drow = &D[(i0-1)*NQ];
        float lval = INFF; int lidx = 0x7fffffff;
        #pragma unroll
        for (int k = 0; k < 5; ++k) {
          int c = lane + (k<<6);
          if ((k < 4 || v4) && !((usedm>>k)&1)) {
            float cur = Drow[c] - ui0 - vvr[k];
            if (cur < minvr[k]) { minvr[k] = cur; wayl[c] = j0; }
            if (minvr[k] < lval) { lval = minvr[k]; lidx = c; }
          }
        }
        #pragma unroll
        for (int m = 1; m < 64; m <<= 1) {
          float ov = __shfl_xor(lval, m); int oj = __shfl_xor(lidx, m);
          if (ov < lval || (ov == lval && oj < lidx)) { lval = ov; lidx = oj; }
        }
        const float delta = lval; j1 = lidx;
        if (lane == 0) uu[it] += delta;      // virtual column (current free row)
        #pragma unroll
        for (int k = 0; k < 5; ++k) {
          if ((usedm>>k)&1) { vvr[k] -= delta; uu[rowc[k]] += delta; }
          else              { minvr[k] -= delta; }
        }
        int pj1 = pcol[j1];
        if (pj1 == 0) break;                 // free column reached
        if (lane == (j1 & 63)) {             // mark scanned, cache its row
          int s = j1 >> 6;
          usedm |= (1 << s);
          #pragma unroll
          for (int k = 0; k < 5; ++k) if (k == s) rowc[k] = pj1;
        }
        j0 = j1; i0 = pj1;
      }
      // augment along 'way' (all lanes lockstep, identical writes)
      int j = j1;
      for (;;) {
        int jp = wayl[j];
        int rr = (jp < 0) ? it : pcol[jp];
        pcol[j] = rr;
        if (jp < 0) break;
        j = jp;
      }
    }
  }
  __syncthreads();

  // matched-pair losses (column's thread owns it)
  if (tid < NQ) {
    int row = pcol[tid];
    if (row > 0) {
      int ti = row-1, q = tid;
      float l1 = fabsf(qraw[q][0]-traw[ti][0]) + fabsf(qraw[q][1]-traw[ti][1])
               + fabsf(qraw[q][2]-traw[ti][2]) + fabsf(qraw[q][3]-traw[ti][3]);
      float lt0=fmaxf(qxy[q][0],txy[ti][0]), lt1=fmaxf(qxy[q][1],txy[ti][1]);
      float rb0=fminf(qxy[q][2],txy[ti][2]), rb1=fminf(qxy[q][3],txy[ti][3]);
      float iw=fmaxf(rb0-lt0,0.f), ih=fmaxf(rb1-lt1,0.f);
      float inter=iw*ih;
      float uni=qarea[q]+tarea[ti]-inter;
      float iou=inter/uni;
      float c0=fminf(qxy[q][0],txy[ti][0]), c1=fminf(qxy[q][1],txy[ti][1]);
      float c2=fmaxf(qxy[q][2],txy[ti][2]), c3=fmaxf(qxy[q][3],txy[ti][3]);
      float cw=fmaxf(c2-c0,0.f), ch=fmaxf(c3-c1,0.f);
      float areac=cw*ch;
      float g=iou-(areac-uni)/areac;
      // focal: replace t=0 term with t=1 term at the matched class
      float x  = logits[((size_t)b*NQ+q)*NC + tlab[ti]];
      float pr = psm[q*NC + tlab[ti]];
      float sp = softplusf(x);
      float term0 = 0.75f*sp*pr*pr;
      float term1 = 0.25f*(sp - x)*(1.f-pr)*(1.f-pr);
      tot += (term1 - term0) + 5.f*l1 + 2.f*(1.f-g);
    }
  }
  // block reduction
  #pragma unroll
  for (int off=32; off; off>>=1) tot += __shfl_down(tot, off);
  if ((tid&63)==0) redw[tid>>6]=tot;
  __syncthreads();
  if (tid==0) {
    float s=0.f;
    for (int w=0; w<NWAVE; ++w) s+=redw[w];
    part[b] = s;
  }
}

__global__ void hm_fin(const float* __restrict__ part, float* __restrict__ out) {
  float s = part[threadIdx.x];
  #pragma unroll
  for (int off=32; off; off>>=1) s += __shfl_down(s, off);
  if (threadIdx.x==0) out[0] = s * (1.0f/1920.0f);
}

extern "C" void kernel_launch(void* const* d_in, const int* in_sizes, int n_in,
                              void* d_out, int out_size, void* d_ws, size_t ws_size,
                              hipStream_t stream) {
  const float* logits = (const float*)d_in[0];
  const float* pbox   = (const float*)d_in[1];
  const int*   labels = (const int*)d_in[2];
  const float* tbox   = (const float*)d_in[3];
  float* partials = (float*)d_ws;   // 64 floats, fully overwritten each launch
  hm_main<<<dim3(64), dim3(NTH), 0, stream>>>(logits, pbox, labels, tbox, partials);
  hm_fin<<<dim3(1), dim3(64), 0, stream>>>(partials, (float*)d_out);
}

// Round 4
// 32.006 us; speedup vs baseline: 2.4242x; 1.2888x over previous
//
#include <hip/hip_runtime.h>
#include <math.h>

#define NQ 300
#define NT 30
#define NC 10
#define NTH 320
#define NWAVE 5
#define INFF 3.0e38f

__device__ __forceinline__ float sigf(float x){ return 1.0f/(1.0f + expf(-x)); }
__device__ __forceinline__ float softplusf(float x){ return fmaxf(x,0.0f) + log1pf(expf(-fabsf(x))); }

// ---- DPP wave64 reductions (result uniform via readlane 63) ----
template<int CTRL,int RMASK>
__device__ __forceinline__ float dppmin_f(float x){
  int t = __builtin_amdgcn_update_dpp(0x7f800000, __float_as_int(x), CTRL, RMASK, 0xf, false);
  return fminf(x, __int_as_float(t));
}
template<int CTRL,int RMASK>
__device__ __forceinline__ unsigned dppmin_u(unsigned x){
  unsigned t = (unsigned)__builtin_amdgcn_update_dpp((int)0xFFFFFFFFu, (int)x, CTRL, RMASK, 0xf, false);
  return x < t ? x : t;
}
template<int CTRL,int RMASK>
__device__ __forceinline__ float dppadd_f(float x){
  int t = __builtin_amdgcn_update_dpp(0, __float_as_int(x), CTRL, RMASK, 0xf, false);
  return x + __int_as_float(t);
}
// argmin with smallest-index tie-break (matches np.argmin first-occurrence)
__device__ __forceinline__ void wave_argmin64(float v, unsigned idx, float &ov, int &oj){
  float x = v;
  x = dppmin_f<0x111,0xf>(x); x = dppmin_f<0x112,0xf>(x);
  x = dppmin_f<0x114,0xf>(x); x = dppmin_f<0x118,0xf>(x);
  x = dppmin_f<0x142,0xa>(x); x = dppmin_f<0x143,0xc>(x);
  float vmin = __int_as_float(__builtin_amdgcn_readlane(__float_as_int(x), 63));
  unsigned c = (v == vmin) ? idx : 0xFFFFFFFFu;
  c = dppmin_u<0x111,0xf>(c); c = dppmin_u<0x112,0xf>(c);
  c = dppmin_u<0x114,0xf>(c); c = dppmin_u<0x118,0xf>(c);
  c = dppmin_u<0x142,0xa>(c); c = dppmin_u<0x143,0xc>(c);
  oj = __builtin_amdgcn_readlane((int)c, 63);
  ov = vmin;
}
__device__ __forceinline__ float wave_sum64(float v){
  float x = v;
  x = dppadd_f<0x111,0xf>(x); x = dppadd_f<0x112,0xf>(x);
  x = dppadd_f<0x114,0xf>(x); x = dppadd_f<0x118,0xf>(x);
  x = dppadd_f<0x142,0xa>(x); x = dppadd_f<0x143,0xc>(x);
  return __int_as_float(__builtin_amdgcn_readlane(__float_as_int(x), 63));
}

// One block per batch element. Waves fill their 6 rows of the 30x300 cost
// matrix (row minima reduced via DPP from live registers); wave 0 does the
// greedy claim (LDS atomicMin) + shortest-augmenting-path for contested rows
// with u,v,minv all in registers; then all threads compute the loss and
// atomicAdd the block partial into d_out (memset to 0 each launch).
__global__ __launch_bounds__(NTH) void hm_main(
    const float* __restrict__ logits,   // [64,300,10]
    const float* __restrict__ pbox,     // [64,300,4] cxcywh
    const int*   __restrict__ labels,   // [64,30]
    const float* __restrict__ tbox,     // [64,30,4] cxcywh
    float* __restrict__ out)            // [1]
{
  const int b = blockIdx.x;
  const int tid = threadIdx.x;
  const int wv = tid >> 6, ln = tid & 63;

  __shared__ float D[NT*NQ];
  __shared__ float psm[NQ*NC];          // sigmoid(logits) table
  __shared__ float qraw[NQ][4], qxy[NQ][4], qarea[NQ];
  __shared__ float traw[NT][4], txy[NT][4], tarea[NT];
  __shared__ int   tlab[NT];
  __shared__ float uu[NT+1];            // row minima handoff to wave 0
  __shared__ int   pcol[NQ];            // 0 = free, else assigned row 1..30
  __shared__ int   wayl[NQ];            // greedy claim array, then SAP predecessors
  __shared__ int   rargm[NT];           // row argmin column
  __shared__ float redw[NWAVE];

  // stage query boxes (raw + xyxy + area)
  for (int q = tid; q < NQ; q += NTH) {
    const float* s = pbox + ((size_t)b*NQ + q)*4;
    float cx=s[0], cy=s[1], w=s[2], h=s[3];
    qraw[q][0]=cx; qraw[q][1]=cy; qraw[q][2]=w; qraw[q][3]=h;
    float x0=cx-0.5f*w, y0=cy-0.5f*h, x1=cx+0.5f*w, y1=cy+0.5f*h;
    qxy[q][0]=x0; qxy[q][1]=y0; qxy[q][2]=x1; qxy[q][3]=y1;
    qarea[q]=(x1-x0)*(y1-y0);
  }
  if (tid < NT) {
    const float* s = tbox + ((size_t)b*NT + tid)*4;
    float cx=s[0], cy=s[1], w=s[2], h=s[3];
    traw[tid][0]=cx; traw[tid][1]=cy; traw[tid][2]=w; traw[tid][3]=h;
    float x0=cx-0.5f*w, y0=cy-0.5f*h, x1=cx+0.5f*w, y1=cy+0.5f*h;
    txy[tid][0]=x0; txy[tid][1]=y0; txy[tid][2]=x1; txy[tid][3]=y1;
    tarea[tid]=(x1-x0)*(y1-y0);
    tlab[tid]=labels[b*NT + tid];
  }
  for (int j = tid; j < NQ; j += NTH) { pcol[j]=0; wayl[j]=0x7fffffff; }

  // sigmoid table + focal t=0 baseline partial sum (all 300x10 logits)
  float tot = 0.f;
  for (int e = tid; e < NQ*NC; e += NTH) {
    float x = logits[(size_t)b*NQ*NC + e];
    float pr = sigf(x);
    psm[e] = pr;
    tot += 0.75f * softplusf(x) * pr * pr;
  }
  __syncthreads();

  // fused cost fill + row minima: wave wv owns rows 6wv..6wv+5, lane ln owns
  // cols ln+64k. D[i][q] = 5*L1 - 2*sigmoid - 2*giou; rowmin via DPP.
  for (int r6 = 0; r6 < 6; ++r6) {
    const int i = wv*6 + r6;
    const float t0=traw[i][0], t1=traw[i][1], t2=traw[i][2], t3=traw[i][3];
    const float x0=txy[i][0], y0=txy[i][1], x1=txy[i][2], y1=txy[i][3];
    const float ta=tarea[i]; const int lab=tlab[i];
    float bv=INFF; unsigned bj=0xFFFFFFFFu;
    #pragma unroll
    for (int k = 0; k < 5; ++k) {
      int q = ln + (k<<6);
      if (k < 4 || ln < (NQ-256)) {
        float cb = fabsf(qraw[q][0]-t0)+fabsf(qraw[q][1]-t1)
                 + fabsf(qraw[q][2]-t2)+fabsf(qraw[q][3]-t3);
        float lt0=fmaxf(qxy[q][0],x0), lt1=fmaxf(qxy[q][1],y0);
        float rb0=fminf(qxy[q][2],x1), rb1=fminf(qxy[q][3],y1);
        float iw=fmaxf(rb0-lt0,0.f), ih=fmaxf(rb1-lt1,0.f);
        float inter=iw*ih;
        float uni=qarea[q]+ta-inter;
        float iou=inter/uni;
        float c0=fminf(qxy[q][0],x0), c1=fminf(qxy[q][1],y0);
        float c2=fmaxf(qxy[q][2],x1), c3=fmaxf(qxy[q][3],y1);
        float cw=fmaxf(c2-c0,0.f), ch=fmaxf(c3-c1,0.f);
        float areac=cw*ch;
        float g=iou-(areac-uni)/areac;
        float dval = 5.f*cb - 2.f*psm[q*NC+lab] - 2.f*g;
        D[i*NQ+q] = dval;
        if (dval < bv) { bv=dval; bj=(unsigned)q; }   // ascending q: first-min kept
      }
    }
    float vmin; int jmin;
    wave_argmin64(bv, bj, vmin, jmin);
    if (ln == 0) { uu[i+1]=vmin; rargm[i]=jmin; }     // u[i] = row min (feasible dual)
  }
  __syncthreads();

  // ---- wave 0: greedy claim + SAP for contested rows ----
  if (tid < 64) {
    const int lane = tid;
    float u_reg = (lane < NT) ? uu[lane+1] : 0.f;     // u duals in registers
    float vvr[5] = {0.f,0.f,0.f,0.f,0.f};             // column duals, col = lane+64k
    const bool v4 = lane < (NQ - 256);
    // greedy: row claims its argmin col; min-row wins (== sequential first-wins)
    int jm = (lane < NT) ? rargm[lane] : 0;
    bool winner = false;
    if (lane < NT) {
      atomicMin(&wayl[jm], lane);                     // wayl doubles as claim array
      winner = (wayl[jm] == lane);
      if (winner) pcol[jm] = lane + 1;
    }
    unsigned freerows = (unsigned)__ballot(lane < NT && !winner);
    // shortest augmenting path for each contested row
    while (freerows) {
      int fr = __builtin_ctz(freerows); freerows &= (freerows - 1);
      const int it = fr + 1;
      float minvr[5] = {INFF,INFF,INFF,INFF,INFF};
      int   usedm = 0;
      bool  onpath = (lane == fr);                    // rows whose u gets +delta
      int   j0 = -1, i0 = it, j1 = 0;
      for (;;) {
        float ui0 = __int_as_float(__builtin_amdgcn_readlane(__float_as_int(u_reg), i0-1));
        const float* Drow = &D[(i0-1)*NQ];
        float lval = INFF; unsigned lidx = 0xFFFFFFFFu;
        #pragma unroll
        for (int k = 0; k < 5; ++k) {
          int c = lane + (k<<6);
          if ((k < 4 || v4) && !((usedm>>k)&1)) {
            float cur = Drow[c] - ui0 - vvr[k];
            if (cur < minvr[k]) { minvr[k] = cur; wayl[c] = j0; }
            if (minvr[k] < lval) { lval = minvr[k]; lidx = (unsigned)c; }
          }
        }
        float delta; int j1i;
        wave_argmin64(lval, lidx, delta, j1i);
        j1 = j1i;
        if (onpath) u_reg += delta;
        #pragma unroll
        for (int k = 0; k < 5; ++k) {
          if ((usedm>>k)&1) vvr[k]  -= delta;
          else              minvr[k] -= delta;
        }
        int pj1 = pcol[j1];                           // uniform broadcast read
        if (pj1 == 0) break;                          // free column reached
        onpath = onpath || (lane == (pj1-1));
        if (lane == (j1 & 63)) usedm |= (1 << (j1 >> 6));
        j0 = j1; i0 = pj1;
      }
      // augment along predecessors (lockstep, identical writes)
      int j = j1;
      for (;;) {
        int jp = wayl[j];
        int rr = (jp < 0) ? it : pcol[jp];
        pcol[j] = rr;
        if (jp < 0) break;
        j = jp;
      }
    }
  }
  __syncthreads();

  // matched-pair losses (column's thread owns it)
  if (tid < NQ) {
    int row = pcol[tid];
    if (row > 0) {
      int ti = row-1, q = tid;
      float l1 = fabsf(qraw[q][0]-traw[ti][0]) + fabsf(qraw[q][1]-traw[ti][1])
               + fabsf(qraw[q][2]-traw[ti][2]) + fabsf(qraw[q][3]-traw[ti][3]);
      float lt0=fmaxf(qxy[q][0],txy[ti][0]), lt1=fmaxf(qxy[q][1],txy[ti][1]);
      float rb0=fminf(qxy[q][2],txy[ti][2]), rb1=fminf(qxy[q][3],txy[ti][3]);
      float iw=fmaxf(rb0-lt0,0.f), ih=fmaxf(rb1-lt1,0.f);
      float inter=iw*ih;
      float uni=qarea[q]+tarea[ti]-inter;
      float iou=inter/uni;
      float c0=fminf(qxy[q][0],txy[ti][0]), c1=fminf(qxy[q][1],txy[ti][1]);
      float c2=fmaxf(qxy[q][2],txy[ti][2]), c3=fmaxf(qxy[q][3],txy[ti][3]);
      float cw=fmaxf(c2-c0,0.f), ch=fmaxf(c3-c1,0.f);
      float areac=cw*ch;
      float g=iou-(areac-uni)/areac;
      // focal: replace t=0 term with t=1 term at the matched class
      float x  = logits[((size_t)b*NQ+q)*NC + tlab[ti]];
      float pr = psm[q*NC + tlab[ti]];
      float sp = softplusf(x);
      float term0 = 0.75f*sp*pr*pr;
      float term1 = 0.25f*(sp - x)*(1.f-pr)*(1.f-pr);
      tot += (term1 - term0) + 5.f*l1 + 2.f*(1.f-g);
    }
  }
  // block reduction: DPP wave sum -> LDS -> single atomicAdd per block
  float wsum = wave_sum64(tot);
  if (ln == 0) redw[wv] = wsum;
  __syncthreads();
  if (tid == 0) {
    float s = redw[0]+redw[1]+redw[2]+redw[3]+redw[4];
    atomicAdd(out, s * (1.0f/1920.0f));
  }
}

extern "C" void kernel_launch(void* const* d_in, const int* in_sizes, int n_in,
                              void* d_out, int out_size, void* d_ws, size_t ws_size,
                              hipStream_t stream) {
  const float* logits = (const float*)d_in[0];
  const float* pbox   = (const float*)d_in[1];
  const int*   labels = (const int*)d_in[2];
  const float* tbox   = (const float*)d_in[3];
  hipMemsetAsync(d_out, 0, sizeof(float), stream);   // out accumulated via atomicAdd
  hm_main<<<dim3(64), dim3(NTH), 0, stream>>>(logits, pbox, labels, tbox, (float*)d_out);
}

// Round 5
// 27.102 us; speedup vs baseline: 2.8630x; 1.1810x over previous
//
#include <hip/hip_runtime.h>
#include <math.h>

#define NQ 300
#define NQP 301              // padded row length for psmT (bank spread on writes)
#define NT 30
#define NC 10
#define NTH 512
#define NWAVE 8
#define INFF 3.0e38f

__device__ __forceinline__ float sigf(float x){ return 1.0f/(1.0f + expf(-x)); }
__device__ __forceinline__ float softplusf(float x){ return fmaxf(x,0.0f) + log1pf(expf(-fabsf(x))); }

// ---- DPP wave64 reductions (result uniform via readlane 63) ----
template<int CTRL,int RMASK>
__device__ __forceinline__ float dppmin_f(float x){
  int t = __builtin_amdgcn_update_dpp(0x7f800000, __float_as_int(x), CTRL, RMASK, 0xf, false);
  return fminf(x, __int_as_float(t));
}
template<int CTRL,int RMASK>
__device__ __forceinline__ unsigned dppmin_u(unsigned x){
  unsigned t = (unsigned)__builtin_amdgcn_update_dpp((int)0xFFFFFFFFu, (int)x, CTRL, RMASK, 0xf, false);
  return x < t ? x : t;
}
template<int CTRL,int RMASK>
__device__ __forceinline__ float dppadd_f(float x){
  int t = __builtin_amdgcn_update_dpp(0, __float_as_int(x), CTRL, RMASK, 0xf, false);
  return x + __int_as_float(t);
}
// argmin with smallest-index tie-break (matches np.argmin first-occurrence)
__device__ __forceinline__ void wave_argmin64(float v, unsigned idx, float &ov, int &oj){
  float x = v;
  x = dppmin_f<0x111,0xf>(x); x = dppmin_f<0x112,0xf>(x);
  x = dppmin_f<0x114,0xf>(x); x = dppmin_f<0x118,0xf>(x);
  x = dppmin_f<0x142,0xa>(x); x = dppmin_f<0x143,0xc>(x);
  float vmin = __int_as_float(__builtin_amdgcn_readlane(__float_as_int(x), 63));
  unsigned c = (v == vmin) ? idx : 0xFFFFFFFFu;
  c = dppmin_u<0x111,0xf>(c); c = dppmin_u<0x112,0xf>(c);
  c = dppmin_u<0x114,0xf>(c); c = dppmin_u<0x118,0xf>(c);
  c = dppmin_u<0x142,0xa>(c); c = dppmin_u<0x143,0xc>(c);
  oj = __builtin_amdgcn_readlane((int)c, 63);
  ov = vmin;
}
__device__ __forceinline__ float wave_sum64(float v){
  float x = v;
  x = dppadd_f<0x111,0xf>(x); x = dppadd_f<0x112,0xf>(x);
  x = dppadd_f<0x114,0xf>(x); x = dppadd_f<0x118,0xf>(x);
  x = dppadd_f<0x142,0xa>(x); x = dppadd_f<0x143,0xc>(x);
  return __int_as_float(__builtin_amdgcn_readlane(__float_as_int(x), 63));
}

// One block per batch element, 8 waves. Waves co-fill the 30x300 cost matrix
// (rows i = wv, wv+8, ...; row minima via DPP from live registers); wave 0
// does the greedy claim (LDS atomicMin) + shortest-augmenting-path for the
// few contested rows with u,v,minv in registers; then all threads compute the
// loss and one atomicAdd per block accumulates into d_out (memset each launch).
__global__ __launch_bounds__(NTH) void hm_main(
    const float* __restrict__ logits,   // [64,300,10]
    const float* __restrict__ pbox,     // [64,300,4] cxcywh
    const int*   __restrict__ labels,   // [64,30]
    const float* __restrict__ tbox,     // [64,30,4] cxcywh
    float* __restrict__ out)            // [1]
{
  const int b = blockIdx.x;
  const int tid = threadIdx.x;
  const int wv = tid >> 6, ln = tid & 63;

  __shared__ float D[NT*NQ];
  __shared__ float psmT[NC*NQP];        // sigmoid table, TRANSPOSED [c][q]
  __shared__ float qraw[NQ][4], qxy[NQ][4], qarea[NQ];
  __shared__ float traw[NT][4], txy[NT][4], tarea[NT];
  __shared__ int   tlab[NT];
  __shared__ float uu[NT+1];            // row minima handoff to wave 0
  __shared__ int   pcol[NQ];            // 0 = free, else assigned row 1..30
  __shared__ int   wayl[NQ];            // greedy claim array, then SAP predecessors
  __shared__ int   rargm[NT];           // row argmin column
  __shared__ float redw[NWAVE];

  // stage query boxes (raw + xyxy + area), vectorized 16B loads
  const float4* pb4 = (const float4*)pbox;
  for (int q = tid; q < NQ; q += NTH) {
    float4 s = pb4[(size_t)b*NQ + q];
    qraw[q][0]=s.x; qraw[q][1]=s.y; qraw[q][2]=s.z; qraw[q][3]=s.w;
    float x0=s.x-0.5f*s.z, y0=s.y-0.5f*s.w, x1=s.x+0.5f*s.z, y1=s.y+0.5f*s.w;
    qxy[q][0]=x0; qxy[q][1]=y0; qxy[q][2]=x1; qxy[q][3]=y1;
    qarea[q]=(x1-x0)*(y1-y0);
  }
  if (tid < NT) {
    float4 s = ((const float4*)tbox)[(size_t)b*NT + tid];
    traw[tid][0]=s.x; traw[tid][1]=s.y; traw[tid][2]=s.z; traw[tid][3]=s.w;
    float x0=s.x-0.5f*s.z, y0=s.y-0.5f*s.w, x1=s.x+0.5f*s.z, y1=s.y+0.5f*s.w;
    txy[tid][0]=x0; txy[tid][1]=y0; txy[tid][2]=x1; txy[tid][3]=y1;
    tarea[tid]=(x1-x0)*(y1-y0);
    tlab[tid]=labels[b*NT + tid];
  }
  for (int j = tid; j < NQ; j += NTH) { pcol[j]=0; wayl[j]=0x7fffffff; }

  // sigmoid table (transposed store) + focal t=0 baseline partial sum
  float tot = 0.f;
  for (int e = tid; e < NQ*NC; e += NTH) {
    float x = logits[(size_t)b*NQ*NC + e];
    float pr = sigf(x);
    int q = e / NC, c = e - q*NC;
    psmT[c*NQP + q] = pr;
    tot += 0.75f * softplusf(x) * pr * pr;
  }
  __syncthreads();

  // fused cost fill + row minima: wave wv owns rows wv, wv+8, ...; lane ln
  // owns cols ln+64k. D[i][q] = 5*L1 - 2*sigmoid - 2*giou; rowmin via DPP.
  for (int i = wv; i < NT; i += NWAVE) {
    const float t0=traw[i][0], t1=traw[i][1], t2=traw[i][2], t3=traw[i][3];
    const float x0=txy[i][0], y0=txy[i][1], x1=txy[i][2], y1=txy[i][3];
    const float ta=tarea[i]; const int lab=tlab[i];
    const float* prow = &psmT[lab*NQP];
    float bv=INFF; unsigned bj=0xFFFFFFFFu;
    #pragma unroll
    for (int k = 0; k < 5; ++k) {
      int q = ln + (k<<6);
      if (k < 4 || ln < (NQ-256)) {
        float cb = fabsf(qraw[q][0]-t0)+fabsf(qraw[q][1]-t1)
                 + fabsf(qraw[q][2]-t2)+fabsf(qraw[q][3]-t3);
        float lt0=fmaxf(qxy[q][0],x0), lt1=fmaxf(qxy[q][1],y0);
        float rb0=fminf(qxy[q][2],x1), rb1=fminf(qxy[q][3],y1);
        float iw=fmaxf(rb0-lt0,0.f), ih=fmaxf(rb1-lt1,0.f);
        float inter=iw*ih;
        float uni=qarea[q]+ta-inter;
        float iou=inter/uni;
        float c0=fminf(qxy[q][0],x0), c1=fminf(qxy[q][1],y0);
        float c2=fmaxf(qxy[q][2],x1), c3=fmaxf(qxy[q][3],y1);
        float cw=fmaxf(c2-c0,0.f), ch=fmaxf(c3-c1,0.f);
        float areac=cw*ch;
        float g=iou-(areac-uni)/areac;
        float dval = 5.f*cb - 2.f*prow[q] - 2.f*g;
        D[i*NQ+q] = dval;
        if (dval < bv) { bv=dval; bj=(unsigned)q; }   // ascending q: first-min kept
      }
    }
    float vmin; int jmin;
    wave_argmin64(bv, bj, vmin, jmin);
    if (ln == 0) { uu[i+1]=vmin; rargm[i]=jmin; }     // u[i] = row min (feasible dual)
  }
  __syncthreads();

  // ---- wave 0: greedy claim + SAP for contested rows ----
  if (tid < 64) {
    const int lane = tid;
    float u_reg = (lane < NT) ? uu[lane+1] : 0.f;     // u duals in registers
    float vvr[5] = {0.f,0.f,0.f,0.f,0.f};             // column duals, col = lane+64k
    const bool v4 = lane < (NQ - 256);
    // greedy: row claims its argmin col; min-row wins (== sequential first-wins)
    int jm = (lane < NT) ? rargm[lane] : 0;
    bool winner = false;
    if (lane < NT) {
      atomicMin(&wayl[jm], lane);                     // wayl doubles as claim array
      winner = (wayl[jm] == lane);
      if (winner) pcol[jm] = lane + 1;
    }
    unsigned freerows = (unsigned)__ballot(lane < NT && !winner);
    // shortest augmenting path for each contested row
    while (freerows) {
      int fr = __builtin_ctz(freerows); freerows &= (freerows - 1);
      const int it = fr + 1;
      float minvr[5] = {INFF,INFF,INFF,INFF,INFF};
      int   usedm = 0;
      bool  onpath = (lane == fr);                    // rows whose u gets +delta
      int   j0 = -1, i0 = it, j1 = 0;
      for (;;) {
        float ui0 = __int_as_float(__builtin_amdgcn_readlane(__float_as_int(u_reg), i0-1));
        const float* Drow = &D[(i0-1)*NQ];
        float lval = INFF; unsigned lidx = 0xFFFFFFFFu;
        #pragma unroll
        for (int k = 0; k < 5; ++k) {
          int c = lane + (k<<6);
          if ((k < 4 || v4) && !((usedm>>k)&1)) {
            float cur = Drow[c] - ui0 - vvr[k];
            if (cur < minvr[k]) { minvr[k] = cur; wayl[c] = j0; }
            if (minvr[k] < lval) { lval = minvr[k]; lidx = (unsigned)c; }
          }
        }
        float delta; int j1i;
        wave_argmin64(lval, lidx, delta, j1i);
        j1 = j1i;
        if (onpath) u_reg += delta;
        #pragma unroll
        for (int k = 0; k < 5; ++k) {
          if ((usedm>>k)&1) vvr[k]  -= delta;
          else              minvr[k] -= delta;
        }
        int pj1 = pcol[j1];                           // uniform broadcast read
        if (pj1 == 0) break;                          // free column reached
        onpath = onpath || (lane == (pj1-1));
        if (lane == (j1 & 63)) usedm |= (1 << (j1 >> 6));
        j0 = j1; i0 = pj1;
      }
      // augment along predecessors (lockstep, identical writes)
      int j = j1;
      for (;;) {
        int jp = wayl[j];
        int rr = (jp < 0) ? it : pcol[jp];
        pcol[j] = rr;
        if (jp < 0) break;
        j = jp;
      }
    }
  }
  __syncthreads();

  // matched-pair losses (column's thread owns it)
  if (tid < NQ) {
    int row = pcol[tid];
    if (row > 0) {
      int ti = row-1, q = tid;
      float l1 = fabsf(qraw[q][0]-traw[ti][0]) + fabsf(qraw[q][1]-traw[ti][1])
               + fabsf(qraw[q][2]-traw[ti][2]) + fabsf(qraw[q][3]-traw[ti][3]);
      float lt0=fmaxf(qxy[q][0],txy[ti][0]), lt1=fmaxf(qxy[q][1],txy[ti][1]);
      float rb0=fminf(qxy[q][2],txy[ti][2]), rb1=fminf(qxy[q][3],txy[ti][3]);
      float iw=fmaxf(rb0-lt0,0.f), ih=fmaxf(rb1-lt1,0.f);
      float inter=iw*ih;
      float uni=qarea[q]+tarea[ti]-inter;
      float iou=inter/uni;
      float c0=fminf(qxy[q][0],txy[ti][0]), c1=fminf(qxy[q][1],txy[ti][1]);
      float c2=fmaxf(qxy[q][2],txy[ti][2]), c3=fmaxf(qxy[q][3],txy[ti][3]);
      float cw=fmaxf(c2-c0,0.f), ch=fmaxf(c3-c1,0.f);
      float areac=cw*ch;
      float g=iou-(areac-uni)/areac;
      // focal: replace t=0 term with t=1 term at the matched class
      float x  = logits[((size_t)b*NQ+q)*NC + tlab[ti]];
      float pr = psmT[tlab[ti]*NQP + q];
      float sp = softplusf(x);
      float term0 = 0.75f*sp*pr*pr;
      float term1 = 0.25f*(sp - x)*(1.f-pr)*(1.f-pr);
      tot += (term1 - term0) + 5.f*l1 + 2.f*(1.f-g);
    }
  }
  // block reduction: DPP wave sum -> LDS -> single atomicAdd per block
  float wsum = wave_sum64(tot);
  if (ln == 0) redw[wv] = wsum;
  __syncthreads();
  if (tid == 0) {
    float s = 0.f;
    #pragma unroll
    for (int w = 0; w < NWAVE; ++w) s += redw[w];
    atomicAdd(out, s * (1.0f/1920.0f));
  }
}

extern "C" void kernel_launch(void* const* d_in, const int* in_sizes, int n_in,
                              void* d_out, int out_size, void* d_ws, size_t ws_size,
                              hipStream_t stream) {
  const float* logits = (const float*)d_in[0];
  const float* pbox   = (const float*)d_in[1];
  const int*   labels = (const int*)d_in[2];
  const float* tbox   = (const float*)d_in[3];
  hipMemsetAsync(d_out, 0, sizeof(float), stream);   // out accumulated via atomicAdd
  hm_main<<<dim3(64), dim3(NTH), 0, stream>>>(logits, pbox, labels, tbox, (float*)d_out);
}